// Round 12
// baseline (223.874 us; speedup 1.0000x reference)
//
#include <hip/hip_runtime.h>
#include <hip/hip_bf16.h>
#include <stdint.h>

#define DIM 64
#define TH  256
#define NN  512
#define IB  4            // queries (i) per main block

typedef __attribute__((ext_vector_type(8))) short bf16x8;
typedef __attribute__((ext_vector_type(4))) float f32x4;

__device__ __forceinline__ short f2bf(float f) {
    union { float f; uint32_t u; } v; v.f = f;
    uint32_t r = v.u + 0x7fffu + ((v.u >> 16) & 1u);
    return (short)(r >> 16);
}

// prep:
//  bid < 256:        8 j's per block: qkv = x@w_qkv; V f32; Kneg bf16 = -k; QW1 f32
//  bid in [256,320): 64 blocks x 4 t's: Bext bf16 [256 t][128 k] (k<64: M=pos_w2@W1; k>=64: W1) + cb[t]
//                    (was 8 blocks x 32 t -> latency-bound long pole ~30-60us; now 64 blocks, LDS-staged col)
__global__ void prep_all(const float* __restrict__ x, const float* __restrict__ w_qkv,
                         const float* __restrict__ attn_w1,
                         const float* __restrict__ pos_w2, const float* __restrict__ pos_b2,
                         const float* __restrict__ attn_b1,
                         float* __restrict__ V, float* __restrict__ QW1, short* __restrict__ Kneg,
                         short* __restrict__ Bg, float* __restrict__ cbg) {
    const int tid = threadIdx.x;  // 256
    if (blockIdx.x >= 256) {
        __shared__ float colW[64][4];           // attn_w1[d][t0+c], bank-conflict-free layout
        const int t0 = (blockIdx.x - 256) * 4;
        const int dw = tid >> 2, c = tid & 3;   // writer: (d, c)
        colW[dw][c] = attn_w1[dw * TH + t0 + c];
        __syncthreads();
        const int h = tid >> 2;                 // reader: (h, c)
        float m = 0.f;
        #pragma unroll 4
        for (int dd = 0; dd < DIM; dd += 4) {
            float4 pw = *(const float4*)&pos_w2[h * DIM + dd];
            m += pw.x * colW[dd][c] + pw.y * colW[dd + 1][c] +
                 pw.z * colW[dd + 2][c] + pw.w * colW[dd + 3][c];
        }
        Bg[(t0 + c) * 128 + h] = f2bf(m);
        Bg[(t0 + c) * 128 + 64 + h] = f2bf(attn_w1[h * TH + t0 + c]);
        if (h == 0) {
            float cb = attn_b1[t0 + c];
            for (int dd = 0; dd < DIM; dd++) cb += pos_b2[dd] * colW[dd][c];
            cbg[t0 + c] = cb;
        }
        return;
    }
    const int b = blockIdx.x >> 6, j0 = (blockIdx.x & 63) * 8;
    __shared__ float xs[8][DIM], qs[8][DIM];
    #pragma unroll
    for (int p = 0; p < 2; p++) {
        int idx = tid + p * 256;
        xs[idx >> 6][idx & 63] = x[(size_t)(b * NN + j0) * DIM + idx];
    }
    __syncthreads();
    if (tid < 192) {
        float acc[8] = {};
        for (int e = 0; e < DIM; e++) {
            float wq = w_qkv[e * 192 + tid];
            #pragma unroll
            for (int jj = 0; jj < 8; jj++) acc[jj] += xs[jj][e] * wq;
        }
        #pragma unroll
        for (int jj = 0; jj < 8; jj++) {
            size_t row = (size_t)(b * NN + j0 + jj) * DIM;
            if (tid < 64)       qs[jj][tid] = acc[jj];
            else if (tid < 128) Kneg[row + (tid - 64)] = f2bf(-acc[jj]);
            else                V[row + (tid - 128)] = acc[jj];
        }
    }
    __syncthreads();
    float aq[8] = {};
    for (int d = 0; d < DIM; d++) {
        float w = attn_w1[d * TH + tid];
        #pragma unroll
        for (int jj = 0; jj < 8; jj++) aq[jj] += qs[jj][d] * w;
    }
    #pragma unroll
    for (int jj = 0; jj < 8; jj++)
        QW1[(size_t)(b * NN + j0 + jj) * TH + tid] = aq[jj];
}

// 8 waves, 2 j-passes/wave (32 j each) -> knf16+gfr16+sa8 regs: live ~100 total (incl AGPR)
// so 2 blocks/CU fit naturally under (512,2). NO tight cap (r3/r9 spill lesson).
__launch_bounds__(512, 2)
__global__ void ptl_main(const float* __restrict__ pos, const float* __restrict__ pos_w1,
                         const float* __restrict__ pos_b1, const float* __restrict__ pos_w2,
                         const float* __restrict__ pos_b2, const float* __restrict__ attn_w2,
                         const float* __restrict__ V, const float* __restrict__ QW1,
                         const short* __restrict__ Kneg, const short* __restrict__ Bg,
                         const float* __restrict__ cbg, float* __restrict__ out) {
    const int b = blockIdx.x >> 7, i0 = (blockIdx.x & 127) * IB;
    const int tid = threadIdx.x;
    const int wv = tid >> 6, lane = tid & 63;
    const int lhi = lane >> 4, llo = lane & 15;

    __shared__ __align__(16) short Blds[128 * 128]; // 32KB: one t-half; row t (256B=16 segs), seg s at ((s^(t&15))<<4)
    __shared__ float posl[NN][3];                    // 6144
    __shared__ float2 qwl[IB][TH];                   // 8192: {QW1[i,t]+cb[t], w2[t]}
    __shared__ float4 pw4[DIM];                      // 1024
    __shared__ float simbuf[IB][NN];                 // 8192 (accumulated across halves; reused as attn)
    __shared__ float aggw[8][IB][2][DIM];            // 16384
    __shared__ float fin[IB][2][DIM];                // 2048
    __shared__ float wred[2][IB][8];                 // 256   => total ~73.5KB -> 2 blocks/CU by LDS

    // ---- common stage ----
    for (int idx = tid; idx < NN * 3; idx += 512)
        ((float*)posl)[idx] = pos[b * NN * 3 + idx];
    if (tid < TH) {
        float w2 = attn_w2[tid], cb = cbg[tid];
        #pragma unroll
        for (int ii = 0; ii < IB; ii++) {
            float2 q2; q2.x = QW1[(size_t)(b * NN + i0 + ii) * TH + tid] + cb; q2.y = w2;
            qwl[ii][tid] = q2;
        }
    }
    if (tid < DIM) {
        float4 w; w.x = pos_w1[tid]; w.y = pos_w1[DIM + tid];
        w.z = pos_w1[2 * DIM + tid]; w.w = pos_b1[tid];
        pw4[tid] = w;
    }

    const char* mb = (const char*)Blds + llo * 256;
    const int s0 = ((0  + lhi) ^ llo) << 4;
    const int s1 = ((4  + lhi) ^ llo) << 4;
    const int s2 = ((8  + lhi) ^ llo) << 4;
    const int s3 = ((12 + lhi) ^ llo) << 4;

    // ---- main: t-half OUTER (stage 32KB once each), j-pass MIDDLE, ii INNER ----
    #pragma unroll 1
    for (int half = 0; half < 2; half++) {
        __syncthreads();                             // prev half/prologue reads done
        for (int idx = tid; idx < 128 * 16; idx += 512) {
            int t = idx >> 4, s = idx & 15;
            *(uint4*)((char*)Blds + t * 256 + ((s ^ (t & 15)) << 4)) =
                *(const uint4*)((const char*)Bg + ((size_t)half * 2048 + idx) * 16);
        }
        __syncthreads();

        #pragma unroll 1
        for (int p = 0; p < 2; p++) {
            const int jbase = p * 256 + wv * 32;
            // Kneg fragments for this pass's 32 j's (16 regs)
            bf16x8 knf[2][2];
            #pragma unroll
            for (int jt = 0; jt < 2; jt++) {
                size_t row = (size_t)(b * NN + jbase + jt * 16 + llo) * DIM;
                knf[jt][0] = *(const bf16x8*)(Kneg + row + lhi * 8);
                knf[jt][1] = *(const bf16x8*)(Kneg + row + 32 + lhi * 8);
            }
            #pragma unroll 1
            for (int ii = 0; ii < IB; ii++) {
                const float pi0 = posl[i0 + ii][0], pi1 = posl[i0 + ii][1], pi2 = posl[i0 + ii][2];
                bf16x8 gfr[2][2];
                #pragma unroll
                for (int jt = 0; jt < 2; jt++) {
                    const int jA = jbase + jt * 16 + llo;
                    const float r0 = pi0 - posl[jA][0], r1 = pi1 - posl[jA][1], r2 = pi2 - posl[jA][2];
                    #pragma unroll
                    for (int kk = 0; kk < 2; kk++) {
                        #pragma unroll
                        for (int e2 = 0; e2 < 4; e2++) {
                            float4 wA = pw4[kk * 32 + lhi * 8 + 2 * e2];
                            float4 wB = pw4[kk * 32 + lhi * 8 + 2 * e2 + 1];
                            float2 p2;
                            p2.x = fmaxf(r0 * wA.x + r1 * wA.y + r2 * wA.z + wA.w, 0.f);
                            p2.y = fmaxf(r0 * wB.x + r1 * wB.y + r2 * wB.z + wB.w, 0.f);
                            union { __hip_bfloat162 h2; uint32_t u; } cv;
                            cv.h2 = __float22bfloat162_rn(p2);
                            ((uint32_t*)&gfr[jt][kk])[e2] = cv.u;
                        }
                    }
                }
                float sa[2][4] = {};
                #pragma unroll 4
                for (int tt = 0; tt < 8; tt++) {
                    const int t = half * 128 + tt * 16 + llo;
                    bf16x8 bf0 = *(const bf16x8*)(mb + tt * 4096 + s0);
                    bf16x8 bf1 = *(const bf16x8*)(mb + tt * 4096 + s1);
                    bf16x8 bf2 = *(const bf16x8*)(mb + tt * 4096 + s2);
                    bf16x8 bf3 = *(const bf16x8*)(mb + tt * 4096 + s3);
                    const float2 qw = qwl[ii][t];
                    #pragma unroll
                    for (int jt = 0; jt < 2; jt++) {
                        f32x4 acc = {qw.x, qw.x, qw.x, qw.x};   // fold +qcb into MFMA C-in
                        acc = __builtin_amdgcn_mfma_f32_16x16x32_bf16(gfr[jt][0], bf0, acc, 0, 0, 0);
                        acc = __builtin_amdgcn_mfma_f32_16x16x32_bf16(gfr[jt][1], bf1, acc, 0, 0, 0);
                        acc = __builtin_amdgcn_mfma_f32_16x16x32_bf16(knf[jt][0], bf2, acc, 0, 0, 0);
                        acc = __builtin_amdgcn_mfma_f32_16x16x32_bf16(knf[jt][1], bf3, acc, 0, 0, 0);
                        #pragma unroll
                        for (int r = 0; r < 4; r++)
                            sa[jt][r] += fmaxf(acc[r], 0.f) * qw.y;
                    }
                }
                #pragma unroll
                for (int jt = 0; jt < 2; jt++) {
                    #pragma unroll
                    for (int r = 0; r < 4; r++) {
                        float v = sa[jt][r];
                        v += __shfl_xor(v, 1); v += __shfl_xor(v, 2);
                        v += __shfl_xor(v, 4); v += __shfl_xor(v, 8);
                        if (llo == 0) {
                            const int j = jbase + jt * 16 + lhi * 4 + r;
                            if (half == 0) simbuf[ii][j] = v;
                            else           simbuf[ii][j] += v;
                        }
                    }
                }
            }
        }
    }
    __syncthreads();

    // ---- softmax per i over j (thread = j) ----
    float sv[IB];
    #pragma unroll
    for (int ii = 0; ii < IB; ii++) {
        float s = simbuf[ii][tid];
        sv[ii] = s;
        float mx = s;
        #pragma unroll
        for (int off = 1; off < 64; off <<= 1) mx = fmaxf(mx, __shfl_xor(mx, off));
        if (lane == 0) wred[0][ii][wv] = mx;
    }
    __syncthreads();
    float pv[IB];
    #pragma unroll
    for (int ii = 0; ii < IB; ii++) {
        float bm = wred[0][ii][0];
        #pragma unroll
        for (int w = 1; w < 8; w++) bm = fmaxf(bm, wred[0][ii][w]);
        float p = __expf(sv[ii] - bm);
        pv[ii] = p;
        float ps = p;
        #pragma unroll
        for (int off = 1; off < 64; off <<= 1) ps += __shfl_xor(ps, off);
        if (lane == 0) wred[1][ii][wv] = ps;
    }
    __syncthreads();
    #pragma unroll
    for (int ii = 0; ii < IB; ii++) {
        float den = 0.f;
        #pragma unroll
        for (int w = 0; w < 8; w++) den += wred[1][ii][w];
        simbuf[ii][tid] = pv[ii] / den;    // attn
    }
    __syncthreads();

    // ---- aggregation: out = attn@V + (attn@G)@pos_w2 + pos_b2; wave = 64-j range, lane = d ----
    {
        const int d = lane;
        const float4 wd = pw4[d];
        float pia[IB][3];
        #pragma unroll
        for (int ii = 0; ii < IB; ii++) {
            pia[ii][0] = posl[i0 + ii][0]; pia[ii][1] = posl[i0 + ii][1]; pia[ii][2] = posl[i0 + ii][2];
        }
        float av[IB] = {}, ag[IB] = {};
        const float* vb = V + (size_t)(b * NN + wv * 64) * DIM + d;
        #pragma unroll 4
        for (int jj = 0; jj < 64; jj++) {
            const int j = wv * 64 + jj;
            const float vv = vb[jj * DIM];
            const float p0 = posl[j][0], p1 = posl[j][1], p2 = posl[j][2];
            #pragma unroll
            for (int ii = 0; ii < IB; ii++) {
                const float a = simbuf[ii][j];
                av[ii] += a * vv;
                float g = (pia[ii][0] - p0) * wd.x + (pia[ii][1] - p1) * wd.y +
                          (pia[ii][2] - p2) * wd.z + wd.w;
                ag[ii] += a * fmaxf(g, 0.f);
            }
        }
        #pragma unroll
        for (int ii = 0; ii < IB; ii++) {
            aggw[wv][ii][0][d] = av[ii];
            aggw[wv][ii][1][d] = ag[ii];
        }
    }
    __syncthreads();
    {   // reduce over 8 waves: one elem per thread (IB*2*64 = 512)
        const int ii = tid >> 7, pp = (tid >> 6) & 1, d2 = tid & 63;
        float s = 0.f;
        #pragma unroll
        for (int w = 0; w < 8; w++) s += aggw[w][ii][pp][d2];
        fin[ii][pp][d2] = s;
    }
    __syncthreads();
    if (tid < IB * DIM) {
        const int ii = tid >> 6, d2 = tid & 63;
        float o = fin[ii][0][d2] + pos_b2[d2];
        for (int h = 0; h < DIM; h++) o += fin[ii][1][h] * pos_w2[h * DIM + d2];
        out[(size_t)(b * NN + i0 + ii) * DIM + d2] = o;
    }
}

extern "C" void kernel_launch(void* const* d_in, const int* in_sizes, int n_in,
                              void* d_out, int out_size, void* d_ws, size_t ws_size,
                              hipStream_t stream) {
    const float* x       = (const float*)d_in[0];
    const float* pos     = (const float*)d_in[1];
    const float* w_qkv   = (const float*)d_in[2];
    const float* pos_w1  = (const float*)d_in[3];
    const float* pos_b1  = (const float*)d_in[4];
    const float* pos_w2  = (const float*)d_in[5];
    const float* pos_b2  = (const float*)d_in[6];
    const float* attn_w1 = (const float*)d_in[7];
    const float* attn_b1 = (const float*)d_in[8];
    const float* attn_w2 = (const float*)d_in[9];
    // attn_b2 (d_in[10]) is softmax-invariant -> unused

    char* ws = (char*)d_ws;
    short* Bg   = (short*)(ws + 0);          //  65536 B  Bext bf16 [256][128]
    float* cbg  = (float*)(ws + 65536);      //   1024 B
    float* Vw   = (float*)(ws + 66560);      // 524288 B  V f32
    float* QW1  = (float*)(ws + 590848);     // 2097152 B q@W1 f32
    short* Kneg = (short*)(ws + 2688000);    // 262144 B  -k bf16   (total ~2.95 MB)

    float* outp = (float*)d_out;

    prep_all<<<320, 256, 0, stream>>>(x, w_qkv, attn_w1, pos_w2, pos_b2, attn_b1,
                                      Vw, QW1, Kneg, Bg, cbg);
    ptl_main<<<4 * (NN / IB), 512, 0, stream>>>(pos, pos_w1, pos_b1, pos_w2, pos_b2,
                                                attn_w2, Vw, QW1, Kneg, Bg, cbg, outp);
}